// Round 1
// baseline (1730.499 us; speedup 1.0000x reference)
//
#include <hip/hip_runtime.h>
#include <math.h>

// Problem constants (fixed by the reference setup)
#define NB     32
#define NA     1024
#define NEIGH  64
#define NTYPE  4
#define NWAVE  16
#define PPB    (NA * NEIGH)        // 65536 pairs per batch
#define NPAIRS (NB * PPB)          // 2,097,152 pairs
#define TOTATOM (NB * NA)          // 32768
#define DENS_ELEMS (TOTATOM * NTYPE * NWAVE)  // 2,097,152 floats (== out_size)
#define CUTOFF_INV (1.0f / 5.0f)
#define PI_F 3.14159265358979323846f

// One thread per pair: compute r, fc, 16-wave radial, scatter-add into dens.
__global__ __launch_bounds__(256) void radial_pair_kernel(
    const float* __restrict__ coords,      // [TOTATOM*3]
    const float* __restrict__ shifts,      // [NPAIRS*3]
    const float* __restrict__ rs,          // [NTYPE*NWAVE]
    const float* __restrict__ inta,        // [NTYPE*NWAVE]
    const int*   __restrict__ atom_index,  // [NB*2*PPB]
    const int*   __restrict__ species,     // [TOTATOM]
    float*       __restrict__ dens)        // [TOTATOM*NTYPE*NWAVE]
{
    int p = blockIdx.x * blockDim.x + threadIdx.x;
    if (p >= NPAIRS) return;

    int b  = p >> 16;          // p / PPB  (PPB = 65536)
    int pp = p & (PPB - 1);    // p % PPB

    // atom_index layout: (NB, 2, PPB)
    int i = atom_index[(b * 2 + 0) * PPB + pp] + b * NA;  // center (global)
    int j = atom_index[(b * 2 + 1) * PPB + pp] + b * NA;  // neighbor (global)

    float sx = shifts[p * 3 + 0];
    float sy = shifts[p * 3 + 1];
    float sz = shifts[p * 3 + 2];
    bool valid = (sx > -1e9f) && (sy > -1e9f) && (sz > -1e9f);

    float dx = coords[i * 3 + 0] - coords[j * 3 + 0] + sx;
    float dy = coords[i * 3 + 1] - coords[j * 3 + 1] + sy;
    float dz = coords[i * 3 + 2] - coords[j * 3 + 2] + sz;
    float r  = sqrtf(dx * dx + dy * dy + dz * dz);

    int spec = species[i];

    // cosine cutoff: 0.5*(cos(pi*min(r/rc,1))+1)
    float x  = fminf(r * CUTOFF_INV, 1.0f);
    float fc = 0.5f * (__cosf(x * PI_F) + 1.0f);
    if (!valid) fc = 0.0f;

    const float* rsrow   = rs   + spec * NWAVE;
    const float* intarow = inta + spec * NWAVE;
    float* dst = dens + (i * NTYPE + spec) * NWAVE;

    #pragma unroll
    for (int w = 0; w < NWAVE; ++w) {
        float d   = r - rsrow[w];
        float val = fc * __expf(-10.0f * intarow[w] * d * d);
        atomicAdd(dst + w, val);
    }
}

// In-place square of dens -> output, float4-vectorized (DENS_ELEMS % 4 == 0).
__global__ __launch_bounds__(256) void square_kernel(float* __restrict__ out)
{
    int i = blockIdx.x * blockDim.x + threadIdx.x;
    if (i * 4 >= DENS_ELEMS) return;
    float4* p = reinterpret_cast<float4*>(out) + i;
    float4 v = *p;
    v.x *= v.x; v.y *= v.y; v.z *= v.z; v.w *= v.w;
    *p = v;
}

extern "C" void kernel_launch(void* const* d_in, const int* in_sizes, int n_in,
                              void* d_out, int out_size, void* d_ws, size_t ws_size,
                              hipStream_t stream) {
    const float* coords     = (const float*)d_in[0];  // coordinates (NB,NA,3)
    const float* shifts     = (const float*)d_in[1];  // (NB,P,3)
    const float* rs         = (const float*)d_in[2];  // (NTYPE,NWAVE)
    const float* inta       = (const float*)d_in[3];  // (NTYPE,NWAVE)
    // d_in[4] params, d_in[5] numatoms: unused in forward
    const int*   atom_index = (const int*)d_in[6];    // (NB,2,P)
    const int*   species    = (const int*)d_in[7];    // (NB*NA,)
    float* out = (float*)d_out;                       // (TOTATOM, NTYPE*NWAVE)

    // Zero the accumulator (d_out doubles as dens buffer).
    hipMemsetAsync(d_out, 0, (size_t)DENS_ELEMS * sizeof(float), stream);

    // Pair scatter kernel.
    {
        dim3 block(256);
        dim3 grid((NPAIRS + 255) / 256);
        radial_pair_kernel<<<grid, block, 0, stream>>>(
            coords, shifts, rs, inta, atom_index, species, out);
    }

    // Square in place.
    {
        int nvec = DENS_ELEMS / 4;
        dim3 block(256);
        dim3 grid((nvec + 255) / 256);
        square_kernel<<<grid, block, 0, stream>>>(out);
    }
}

// Round 3
// 183.154 us; speedup vs baseline: 9.4483x; 9.4483x over previous
//
#include <hip/hip_runtime.h>
#include <math.h>

// Problem constants (fixed by the reference setup)
#define NB     32
#define NA     1024
#define NEIGH  64
#define NTYPE  4
#define NWAVE  16
#define PPB    (NA * NEIGH)        // 65536 pairs per batch
#define NPAIRS (NB * PPB)          // 2,097,152 pairs
#define TOTATOM (NB * NA)          // 32768
#define DENS_ELEMS (TOTATOM * NTYPE * NWAVE)  // 2,097,152 floats (== out_size)
#define CUTOFF_INV (1.0f / 5.0f)
#define PI_F 3.14159265358979323846f

#define NSPLIT 8                   // blocks per batch
#define BLOCK  512
#define PAIRS_PER_BLOCK (PPB / NSPLIT)   // 8192
#define WS_NEEDED ((size_t)NB * NSPLIT * NA * NWAVE * sizeof(float))  // 16 MiB

// ---------------------------------------------------------------------------
// Main path: per-batch LDS privatization.
// Block (b, s): accumulate 8192 pairs of batch b into a 64 KB LDS density
// slice [NA][NWAVE] (swizzled), then stream the partial to workspace.
// ---------------------------------------------------------------------------
__global__ __launch_bounds__(BLOCK) void radial_pair_lds(
    const float* __restrict__ coords,      // [TOTATOM*3]
    const float* __restrict__ shifts,      // [NPAIRS*3]
    const float* __restrict__ rs,          // [NTYPE*NWAVE]
    const float* __restrict__ inta,        // [NTYPE*NWAVE]
    const int*   __restrict__ atom_index,  // [NB*2*PPB]
    const int*   __restrict__ species,     // [TOTATOM]
    float*       __restrict__ part)        // [NB*NSPLIT][NA*NWAVE]
{
    __shared__ float sdens[NA * NWAVE];    // 64 KiB
    __shared__ float srs[NTYPE * NWAVE];
    __shared__ float sinta[NTYPE * NWAVE];

    const int b   = blockIdx.x / NSPLIT;
    const int s   = blockIdx.x % NSPLIT;
    const int tid = threadIdx.x;

    if (tid < NTYPE * NWAVE) {
        srs[tid]   = rs[tid];
        sinta[tid] = inta[tid];
    }
    #pragma unroll
    for (int k = 0; k < (NA * NWAVE) / BLOCK; ++k)
        sdens[k * BLOCK + tid] = 0.0f;
    __syncthreads();

    const int* ai0 = atom_index + (b * 2 + 0) * PPB + s * PAIRS_PER_BLOCK;
    const int* ai1 = atom_index + (b * 2 + 1) * PPB + s * PAIRS_PER_BLOCK;
    const float* cb = coords  + (size_t)b * NA * 3;
    const int*   sb = species + b * NA;
    const float* shb = shifts + ((size_t)b * PPB + s * PAIRS_PER_BLOCK) * 3;

    #pragma unroll 2
    for (int k = 0; k < PAIRS_PER_BLOCK / BLOCK; ++k) {
        const int pp = k * BLOCK + tid;
        const int i = ai0[pp];    // center, local to batch
        const int j = ai1[pp];    // neighbor, local to batch

        const float sx = shb[pp * 3 + 0];
        const float sy = shb[pp * 3 + 1];
        const float sz = shb[pp * 3 + 2];
        const bool valid = (sx > -1e9f) && (sy > -1e9f) && (sz > -1e9f);

        const float dx = cb[i * 3 + 0] - cb[j * 3 + 0] + sx;
        const float dy = cb[i * 3 + 1] - cb[j * 3 + 1] + sy;
        const float dz = cb[i * 3 + 2] - cb[j * 3 + 2] + sz;
        const float r  = sqrtf(dx * dx + dy * dy + dz * dz);

        const int spec = sb[i];

        float x  = fminf(r * CUTOFF_INV, 1.0f);
        float fc = 0.5f * (__cosf(x * PI_F) + 1.0f);
        if (!valid) fc = 0.0f;

        const float* rsrow   = srs   + spec * NWAVE;
        const float* intarow = sinta + spec * NWAVE;
        float* drow = sdens + i * NWAVE;

        #pragma unroll
        for (int w = 0; w < NWAVE; ++w) {
            const float d   = r - rsrow[w];
            const float val = fc * __expf(-10.0f * intarow[w] * d * d);
            // swizzle the wave slot by atom index -> banks spread over all 32
            atomicAdd(drow + ((w + i) & (NWAVE - 1)), val);
        }
    }
    __syncthreads();

    // Stream partial to workspace, unswizzling.
    float* dst = part + ((size_t)(b * NSPLIT + s)) * (NA * NWAVE);
    #pragma unroll
    for (int k = 0; k < (NA * NWAVE) / BLOCK; ++k) {
        const int f = k * BLOCK + tid;
        const int a = f >> 4;
        const int w = f & (NWAVE - 1);
        dst[f] = sdens[a * NWAVE + ((w + a) & (NWAVE - 1))];
    }
}

// Sum the NSPLIT partials per (atom, wave), square, write full output row
// (zeros for the 3 unused type rows). Fully initializes d_out.
__global__ __launch_bounds__(256) void reduce_square(
    const float* __restrict__ part,       // [NB*NSPLIT][NA*NWAVE]
    const int*   __restrict__ species,    // [TOTATOM]
    float*       __restrict__ out)        // [TOTATOM][NTYPE*NWAVE]
{
    const int t = blockIdx.x * blockDim.x + threadIdx.x;
    if (t >= TOTATOM * NWAVE) return;
    const int g = t >> 4;              // global atom
    const int w = t & (NWAVE - 1);
    const int b = g >> 10;             // g / NA
    const int a = g & (NA - 1);

    const float* p = part + ((size_t)b * NSPLIT) * (NA * NWAVE) + a * NWAVE + w;
    float sum = 0.0f;
    #pragma unroll
    for (int s = 0; s < NSPLIT; ++s)
        sum += p[(size_t)s * NA * NWAVE];
    sum *= sum;

    const int spec = species[g];
    float* o = out + (size_t)g * (NTYPE * NWAVE) + w;
    #pragma unroll
    for (int ty = 0; ty < NTYPE; ++ty)
        o[ty * NWAVE] = (ty == spec) ? sum : 0.0f;
}

// ---------------------------------------------------------------------------
// Fallback path (ws too small): round-0 global-atomic version.
// ---------------------------------------------------------------------------
__global__ __launch_bounds__(256) void radial_pair_atomic(
    const float* __restrict__ coords, const float* __restrict__ shifts,
    const float* __restrict__ rs, const float* __restrict__ inta,
    const int* __restrict__ atom_index, const int* __restrict__ species,
    float* __restrict__ dens)
{
    int p = blockIdx.x * blockDim.x + threadIdx.x;
    if (p >= NPAIRS) return;
    int b  = p >> 16;
    int pp = p & (PPB - 1);
    int i = atom_index[(b * 2 + 0) * PPB + pp] + b * NA;
    int j = atom_index[(b * 2 + 1) * PPB + pp] + b * NA;
    float sx = shifts[p * 3 + 0], sy = shifts[p * 3 + 1], sz = shifts[p * 3 + 2];
    bool valid = (sx > -1e9f) && (sy > -1e9f) && (sz > -1e9f);
    float dx = coords[i * 3 + 0] - coords[j * 3 + 0] + sx;
    float dy = coords[i * 3 + 1] - coords[j * 3 + 1] + sy;
    float dz = coords[i * 3 + 2] - coords[j * 3 + 2] + sz;
    float r  = sqrtf(dx * dx + dy * dy + dz * dz);
    int spec = species[i];
    float x  = fminf(r * CUTOFF_INV, 1.0f);
    float fc = 0.5f * (__cosf(x * PI_F) + 1.0f);
    if (!valid) fc = 0.0f;
    const float* rsrow   = rs   + spec * NWAVE;
    const float* intarow = inta + spec * NWAVE;
    float* dst = dens + ((size_t)i * NTYPE + spec) * NWAVE;
    #pragma unroll
    for (int w = 0; w < NWAVE; ++w) {
        float d   = r - rsrow[w];
        float val = fc * __expf(-10.0f * intarow[w] * d * d);
        atomicAdd(dst + w, val);
    }
}

__global__ __launch_bounds__(256) void square_kernel(float* __restrict__ out)
{
    int i = blockIdx.x * blockDim.x + threadIdx.x;
    if (i * 4 >= DENS_ELEMS) return;
    float4* p = reinterpret_cast<float4*>(out) + i;
    float4 v = *p;
    v.x *= v.x; v.y *= v.y; v.z *= v.z; v.w *= v.w;
    *p = v;
}

extern "C" void kernel_launch(void* const* d_in, const int* in_sizes, int n_in,
                              void* d_out, int out_size, void* d_ws, size_t ws_size,
                              hipStream_t stream) {
    const float* coords     = (const float*)d_in[0];
    const float* shifts     = (const float*)d_in[1];
    const float* rs         = (const float*)d_in[2];
    const float* inta       = (const float*)d_in[3];
    const int*   atom_index = (const int*)d_in[6];
    const int*   species    = (const int*)d_in[7];
    float* out = (float*)d_out;

    if (ws_size >= WS_NEEDED) {
        float* part = (float*)d_ws;
        radial_pair_lds<<<dim3(NB * NSPLIT), dim3(BLOCK), 0, stream>>>(
            coords, shifts, rs, inta, atom_index, species, part);
        reduce_square<<<dim3((TOTATOM * NWAVE + 255) / 256), dim3(256), 0, stream>>>(
            part, species, out);
    } else {
        hipMemsetAsync(d_out, 0, (size_t)DENS_ELEMS * sizeof(float), stream);
        radial_pair_atomic<<<dim3((NPAIRS + 255) / 256), dim3(256), 0, stream>>>(
            coords, shifts, rs, inta, atom_index, species, out);
        square_kernel<<<dim3((DENS_ELEMS / 4 + 255) / 256), dim3(256), 0, stream>>>(out);
    }
}